// Round 1
// baseline (6840.409 us; speedup 1.0000x reference)
//
#include <hip/hip_runtime.h>
#include <stdint.h>

#define SEQ 48
#define NL  16
#define NV  32000
#define POLLMAX 4000000

typedef short bf16x8 __attribute__((ext_vector_type(8)));
typedef float f32x4  __attribute__((ext_vector_type(4)));

__device__ __forceinline__ unsigned short f2b(float f) {
    union { float f; unsigned int u; } v; v.f = f;
    unsigned int r = (v.u + 0x7FFFu + ((v.u >> 16) & 1u)) >> 16;
    return (unsigned short)r;
}
__device__ __forceinline__ float b2f(unsigned short s) {
    union { float f; unsigned int u; } v; v.u = ((unsigned int)s) << 16;
    return v.f;
}
__device__ __forceinline__ bf16x8 load_w8(const float* p) {
    const float4* q = (const float4*)p;
    float4 a = q[0], b = q[1];
    bf16x8 r;
    r[0] = (short)f2b(a.x); r[1] = (short)f2b(a.y);
    r[2] = (short)f2b(a.z); r[3] = (short)f2b(a.w);
    r[4] = (short)f2b(b.x); r[5] = (short)f2b(b.y);
    r[6] = (short)f2b(b.z); r[7] = (short)f2b(b.w);
    return r;
}
__device__ __forceinline__ bf16x8 load_b8(const unsigned short* p) {
    return *(const bf16x8*)p;
}
__device__ __forceinline__ f32x4 mfma16(bf16x8 a, bf16x8 b, f32x4 c) {
    return __builtin_amdgcn_mfma_f32_16x16x32_bf16(a, b, c, 0, 0, 0);
}
__device__ __forceinline__ float sigm(float x) { return 1.0f / (1.0f + __expf(-x)); }
__device__ __forceinline__ float tanh_(float x) { return 1.0f - 2.0f / (__expf(2.0f * x) + 1.0f); }

// ---------------- embeddings: gather + bf16 ----------------
__global__ __launch_bounds__(256) void embed_kernel(
    const int* __restrict__ x, const int* __restrict__ y,
    const float* __restrict__ enc_emb, const float* __restrict__ dec_emb,
    unsigned short* __restrict__ xs, unsigned short* __restrict__ ds)
{
    int bid = blockIdx.x;             // 0..1535
    int which = bid >= 768;
    int r = which ? bid - 768 : bid;
    int t = r >> 4, b = r & 15;
    int tok = which ? y[b * SEQ + t] : x[b * SEQ + t];
    const float* src = (which ? dec_emb : enc_emb) + (size_t)tok * 512;
    unsigned short* dst = (which ? ds : xs) + ((size_t)t * 16 + b) * 512;
    for (int k = threadIdx.x; k < 512; k += 256) dst[k] = f2b(src[k]);
}

// ---------------- encoder v2 ----------------
// 18 WGs x 512 threads.
//  bid 0..15  : Stage A producers. WG (dir = bid>>3, pblk = bid&7) owns 128 gate
//               rows; per layer it computes Gx[dir][t][b][row] = Wih@x + bias for
//               all 48 timesteps (in the consumption order of its direction),
//               gated per-timestep on the previous layer's recurrence flags.
//  bid 16,17  : recurrence WG, one per direction. Whole Whh [1024x256] bf16 lives
//               on ONE CU: 6/8 of K in registers (192 VGPR/lane), 2/8 in LDS
//               (128 KB). h exchanged wave<->wave via 8 KB LDS; c in registers.
//               Per-step sync = 2 x __syncthreads, no global round trip.
// Row ownership in rec WG: wave wv owns units [wv*32, wv*32+32) of ALL 4 gates
// (rt = gate*2 + uh), so i/f/g/o for a unit land in the same lane+reg -> the
// LSTM elementwise update is lane-local, no gate gather.
__global__ __launch_bounds__(512, 2) void enc_v2(
    const float* __restrict__ Wih,   // [NL][2][1024][512]
    const float* __restrict__ Whh,   // [NL][2][1024][256]
    const float* __restrict__ bias,  // [NL][2][1024]
    unsigned short* __restrict__ xsA, unsigned short* __restrict__ xsB, // [48][16][512] ping-pong
    unsigned short* __restrict__ dec_h0,  // [NL][16][512] bf16
    float* __restrict__ dec_c0,           // [NL][16][512] fp32
    float* __restrict__ Gx,               // [2 par][2 dir][48][16][1024] fp32 (aliases ds)
    int* __restrict__ recflag,            // [NL][2] stride 16 ints
    int* __restrict__ gxflag)             // [NL][2][8] stride 16 ints
{
    const int tid = threadIdx.x, bid = blockIdx.x;
    const int wv = tid >> 6, lane = tid & 63, q = lane >> 4, ln = lane & 15;

    if (bid < 16) {
        // ================= Stage A: input-GEMM producers =================
        const int dir = bid >> 3, pblk = bid & 7;
        const int gate = wv >> 1, half = wv & 1;
        const int row0 = gate * 256 + pblk * 32 + half * 16;
        for (int l = 0; l < NL; ++l) {
            bf16x8 aih[16];
            const float* wb = Wih + (((size_t)(l * 2 + dir) * 1024) + row0 + ln) * 512;
#pragma unroll
            for (int kt = 0; kt < 16; ++kt) aih[kt] = load_w8(wb + kt * 32 + q * 8);
            const float4 bias4 = *(const float4*)(bias + (size_t)(l * 2 + dir) * 1024 + row0 + q * 4);
            const unsigned short* xin = (l & 1) ? xsB : xsA;
            float* gxl = Gx + (size_t)((l & 1) * 2 + dir) * SEQ * 16 * 1024;
            int* myflag = gxflag + ((l * 2 + dir) * 8 + pblk) * 16;
            const int* rfprev = recflag + (l - 1) * 2 * 16;
            for (int s = 0; s < SEQ; ++s) {
                const int t_src = dir ? (SEQ - 1 - s) : s;
                if (l > 0) {
                    // xs_l[t_src] full <=> own-dir rec(l-1) >= s+1  AND  other-dir >= 48-s
                    if (tid < 64) {
                        if (tid < 2) {
                            const int need = (tid == dir) ? (s + 1) : (SEQ - s);
                            const int* f = rfprev + tid * 16;
                            int it = 0;
                            while (__hip_atomic_load(f, __ATOMIC_RELAXED, __HIP_MEMORY_SCOPE_AGENT) < need)
                                if (++it > POLLMAX) break;
                        }
                        __builtin_amdgcn_fence(__ATOMIC_ACQUIRE, "agent");
                    }
                    __syncthreads();
                }
                const unsigned short* xrow = xin + ((size_t)t_src * 16 + ln) * 512;
                f32x4 acc0 = {0.f,0.f,0.f,0.f}, acc1 = {0.f,0.f,0.f,0.f};
#pragma unroll
                for (int kt = 0; kt < 16; kt += 2) {
                    acc0 = mfma16(aih[kt],     load_b8(xrow + kt * 32 + q * 8),       acc0);
                    acc1 = mfma16(aih[kt + 1], load_b8(xrow + (kt + 1) * 32 + q * 8), acc1);
                }
                unsigned int* gd = (unsigned int*)(gxl + ((size_t)t_src * 16 + ln) * 1024 + row0 + q * 4);
#pragma unroll
                for (int r = 0; r < 4; ++r) {
                    union { float f; unsigned int u; } v;
                    v.f = acc0[r] + acc1[r] + ((const float*)&bias4)[r];
                    __hip_atomic_store(gd + r, v.u, __ATOMIC_RELAXED, __HIP_MEMORY_SCOPE_AGENT);
                }
                __syncthreads();
                if (tid == 0)
                    __hip_atomic_store(myflag, s + 1, __ATOMIC_RELEASE, __HIP_MEMORY_SCOPE_AGENT);
            }
        }
        return;
    }

    // ================= recurrence: one WG per direction =================
    const int dir = bid - 16;
    __shared__ bf16x8 wlds[8][8][2][64];      // 128 KB: K-tiles 6,7 of Whh, lane-private slices
    __shared__ unsigned short h_lds[16][264]; // 8.25 KB: h[b][unit], +8 pad kills bank conflicts

    float cr[2][4];                            // cell state, lane-local
    for (int l = 0; l < NL; ++l) {
        bf16x8 wr[8][6];                       // K-tiles 0..5 of Whh: 192 VGPR/lane
        {
            const float* wb = Whh + (size_t)(l * 2 + dir) * 1024 * 256;
#pragma unroll
            for (int rt = 0; rt < 8; ++rt) {
                const int R = (rt >> 1) * 256 + wv * 32 + (rt & 1) * 16;
                const float* rp = wb + (size_t)(R + ln) * 256 + q * 8;
#pragma unroll
                for (int kt = 0; kt < 6; ++kt) wr[rt][kt] = load_w8(rp + kt * 32);
#pragma unroll
                for (int kt2 = 0; kt2 < 2; ++kt2)
                    wlds[wv][rt][kt2][lane] = load_w8(rp + (6 + kt2) * 32);
            }
        }
        const int* gxf = gxflag + (l * 2 + dir) * 8 * 16;
        int* rf = recflag + (l * 2 + dir) * 16;
        const float* gxl = Gx + (size_t)((l & 1) * 2 + dir) * SEQ * 16 * 1024;
        unsigned short* xout = (l & 1) ? xsA : xsB;
        __syncthreads();

        for (int t = 0; t < SEQ; ++t) {
            const int t_src = dir ? (SEQ - 1 - t) : t;
            // wait for Gx chunk t from all 8 Stage-A producers of this direction
            if (tid < 64) {
                if (tid < 8) {
                    const int* f = gxf + tid * 16;
                    int it = 0;
                    while (__hip_atomic_load(f, __ATOMIC_RELAXED, __HIP_MEMORY_SCOPE_AGENT) < t + 1)
                        if (++it > POLLMAX) break;
                }
                __builtin_amdgcn_fence(__ATOMIC_ACQUIRE, "agent");
            }
            __syncthreads();
            // lagged release: step t-1's xs stores drained by the barrier above
            if (tid == 0 && t > 0)
                __hip_atomic_store(rf, t, __ATOMIC_RELEASE, __HIP_MEMORY_SCOPE_AGENT);

            // acc init from Gx (already includes bias)
            const float* gxt = gxl + ((size_t)t_src * 16 + ln) * 1024 + wv * 32 + q * 4;
            f32x4 acc[8];
#pragma unroll
            for (int rt = 0; rt < 8; ++rt) {
                float4 g4 = *(const float4*)(gxt + (rt >> 1) * 256 + (rt & 1) * 16);
                acc[rt][0] = g4.x; acc[rt][1] = g4.y; acc[rt][2] = g4.z; acc[rt][3] = g4.w;
            }
            // recurrent part: g += h_{t-1} @ Whh^T
            if (t > 0) {
#pragma unroll
                for (int kt = 0; kt < 8; ++kt) {
                    bf16x8 hf = *(const bf16x8*)&h_lds[ln][kt * 32 + q * 8];
#pragma unroll
                    for (int rt = 0; rt < 8; ++rt)
                        acc[rt] = mfma16(kt < 6 ? wr[rt][kt] : wlds[wv][rt][kt - 6][lane], hf, acc[rt]);
                }
            }
            __syncthreads();   // all h_lds reads done before overwrite

            // elementwise LSTM update, lane-local gates
#pragma unroll
            for (int uh = 0; uh < 2; ++uh) {
                unsigned short hb[4];
#pragma unroll
                for (int r = 0; r < 4; ++r) {
                    float gi = acc[0 + uh][r];
                    float gf = acc[2 + uh][r];
                    float gg = acc[4 + uh][r];
                    float go = acc[6 + uh][r];
                    float c  = (t == 0) ? 0.f : cr[uh][r];
                    float cn = sigm(gf) * c + sigm(gi) * tanh_(gg);
                    cr[uh][r] = cn;
                    hb[r] = f2b(sigm(go) * tanh_(cn));
                }
                const int u = wv * 32 + uh * 16 + q * 4;
                uint2 hv;
                hv.x = (unsigned)hb[0] | ((unsigned)hb[1] << 16);
                hv.y = (unsigned)hb[2] | ((unsigned)hb[3] << 16);
                *(uint2*)&h_lds[ln][u] = hv;
                unsigned int* xo = (unsigned int*)(xout + ((size_t)t_src * 16 + ln) * 512 + dir * 256 + u);
                __hip_atomic_store(xo,     hv.x, __ATOMIC_RELAXED, __HIP_MEMORY_SCOPE_AGENT);
                __hip_atomic_store(xo + 1, hv.y, __ATOMIC_RELAXED, __HIP_MEMORY_SCOPE_AGENT);
                if (t == SEQ - 1) {
                    *(uint2*)(dec_h0 + ((size_t)l * 16 + ln) * 512 + dir * 256 + u) = hv;
                    float4 cv; cv.x = cr[uh][0]; cv.y = cr[uh][1]; cv.z = cr[uh][2]; cv.w = cr[uh][3];
                    *(float4*)(dec_c0 + ((size_t)l * 16 + ln) * 512 + dir * 256 + u) = cv;
                }
            }
            // next iteration's poll-barrier separates h_lds writes from reads
        }
        __syncthreads();
        if (tid == 0)
            __hip_atomic_store(rf, SEQ, __ATOMIC_RELEASE, __HIP_MEMORY_SCOPE_AGENT);
    }
}

// ---------------- pipelined decoder: ALL 16 layers concurrent, 512 WGs ----------------
__global__ __launch_bounds__(256, 2) void dec_pipe(
    const float* __restrict__ Wih,   // [NL][2048][512]
    const float* __restrict__ Whh,   // [NL][2048][512]
    const float* __restrict__ bias,  // [NL][2048]
    const unsigned short* __restrict__ demb, // [48][16][512]
    const unsigned short* __restrict__ h0,   // [NL][16][512]
    const float* __restrict__ c0,            // [NL][16][512]
    unsigned short* __restrict__ ds,         // [NL][48][16][512]
    int* __restrict__ flags)                 // [NL][32] stride 16 ints
{
    const int tid = threadIdx.x;
    const int l = blockIdx.x >> 5, p = blockIdx.x & 31;
    const int gate = tid >> 6, lane = tid & 63, q = lane >> 4, ln = lane & 15;
    __shared__ float gsm[4][16][17];
    __shared__ float cbuf[16][17];

    bf16x8 aih[16], ahh[16];
    const size_t row = (size_t)l * 2048 + gate * 512 + p * 16 + ln;
#pragma unroll
    for (int kt = 0; kt < 16; ++kt) aih[kt] = load_w8(Wih + row * 512 + kt * 32 + q * 8);
#pragma unroll
    for (int kt = 0; kt < 16; ++kt) ahh[kt] = load_w8(Whh + row * 512 + kt * 32 + q * 8);
    const float4 bias4 = *(const float4*)(bias + (size_t)l * 2048 + gate * 512 + p * 16 + q * 4);

    const unsigned short* xlayer = (l == 0) ? demb : (ds + (size_t)(l - 1) * SEQ * 16 * 512);
    const int* fin  = flags + (l - 1) * 32 * 16;
    const int* fown = flags + l * 32 * 16;
    int* myflag = flags + (l * 32 + p) * 16;

    for (int t = 0; t < SEQ; ++t) {
        if (tid < 64) {
            if (tid < 32) {
                if (l > 0) {
                    const int* f = fin + tid * 16;
                    int it = 0;
                    while (__hip_atomic_load(f, __ATOMIC_RELAXED, __HIP_MEMORY_SCOPE_AGENT) < t + 1)
                        if (++it > POLLMAX) break;
                }
            } else if (t > 0) {
                const int* f = fown + (tid - 32) * 16;
                int it = 0;
                while (__hip_atomic_load(f, __ATOMIC_RELAXED, __HIP_MEMORY_SCOPE_AGENT) < t)
                    if (++it > POLLMAX) break;
            }
            __builtin_amdgcn_fence(__ATOMIC_ACQUIRE, "agent");
        }
        __syncthreads();

        const unsigned short* xrow = xlayer + ((size_t)t * 16 + ln) * 512;
        const unsigned short* hrow = (t == 0) ? (h0 + ((size_t)l * 16 + ln) * 512)
                                              : (ds + (((size_t)l * SEQ + (t - 1)) * 16 + ln) * 512);
        f32x4 acc0 = {0.f,0.f,0.f,0.f}, acc1 = {0.f,0.f,0.f,0.f};
#pragma unroll
        for (int kt = 0; kt < 16; kt += 2) {
            acc0 = mfma16(aih[kt],     load_b8(xrow + kt * 32 + q * 8),       acc0);
            acc1 = mfma16(aih[kt + 1], load_b8(xrow + (kt + 1) * 32 + q * 8), acc1);
        }
#pragma unroll
        for (int kt = 0; kt < 16; kt += 2) {
            acc0 = mfma16(ahh[kt],     load_b8(hrow + kt * 32 + q * 8),       acc0);
            acc1 = mfma16(ahh[kt + 1], load_b8(hrow + (kt + 1) * 32 + q * 8), acc1);
        }
        gsm[gate][q * 4 + 0][ln] = acc0[0] + acc1[0] + bias4.x;
        gsm[gate][q * 4 + 1][ln] = acc0[1] + acc1[1] + bias4.y;
        gsm[gate][q * 4 + 2][ln] = acc0[2] + acc1[2] + bias4.z;
        gsm[gate][q * 4 + 3][ln] = acc0[3] + acc1[3] + bias4.w;
        __syncthreads();
        if (tid < 128) {
            const int b = tid >> 3, u2 = (tid & 7) * 2;
            unsigned int hv = 0;
#pragma unroll
            for (int s = 0; s < 2; ++s) {
                int u = u2 + s;
                float gi = gsm[0][u][b], gf = gsm[1][u][b], gg = gsm[2][u][b], go = gsm[3][u][b];
                float c = (t == 0) ? c0[((size_t)l * 16 + b) * 512 + p * 16 + u] : cbuf[u][b];
                float cn = sigm(gf) * c + sigm(gi) * tanh_(gg);
                float h = sigm(go) * tanh_(cn);
                cbuf[u][b] = cn;
                hv |= ((unsigned int)f2b(h)) << (16 * s);
            }
            __hip_atomic_store((unsigned int*)(ds + (((size_t)l * SEQ + t) * 16 + b) * 512 + p * 16 + u2),
                               hv, __ATOMIC_RELAXED, __HIP_MEMORY_SCOPE_AGENT);
        }
        __syncthreads();
        if (tid == 0)
            __hip_atomic_store(myflag, t + 1, __ATOMIC_RELEASE, __HIP_MEMORY_SCOPE_AGENT);
    }
}

// ---------------- final projection ----------------
__global__ __launch_bounds__(256) void final_gemm(
    const unsigned short* __restrict__ ds,
    const float* __restrict__ W,
    const float* __restrict__ bias,
    unsigned short* __restrict__ out)
{
    const int tid = threadIdx.x;
    const int w = tid >> 6, lane = tid & 63, q = lane >> 4, ln = lane & 15;
    const int n0 = blockIdx.x * 64;     // 500 blocks
    for (int mb = 0; mb < 12; ++mb) {
        const int m0 = mb * 64 + w * 16;
        bf16x8 afr[16];
#pragma unroll
        for (int kt = 0; kt < 16; ++kt)
            afr[kt] = load_b8(ds + ((size_t)m0 + ln) * 512 + kt * 32 + q * 8);
#pragma unroll
        for (int j = 0; j < 4; ++j) {
            f32x4 acc0 = {0.f,0.f,0.f,0.f}, acc1 = {0.f,0.f,0.f,0.f};
            const float* wb = W + ((size_t)(n0 + j * 16 + ln)) * 512;
#pragma unroll
            for (int kt = 0; kt < 16; kt += 2) {
                bf16x8 b0 = load_w8(wb + kt * 32 + q * 8);
                bf16x8 b1 = load_w8(wb + (kt + 1) * 32 + q * 8);
                acc0 = mfma16(afr[kt], b0, acc0);
                acc1 = mfma16(afr[kt + 1], b1, acc1);
            }
            int n = n0 + j * 16 + ln;
            float bv = bias[n];
#pragma unroll
            for (int r = 0; r < 4; ++r)
                out[((size_t)m0 + q * 4 + r) * NV + n] = f2b(acc0[r] + acc1[r] + bv);
        }
    }
}

// ---------------- transpose: out[b][v][t] (fp32) from ltmp[t*16+b][v] (bf16) ----------------
__global__ __launch_bounds__(256) void transpose_out(
    const unsigned short* __restrict__ tmp, float* __restrict__ out)
{
    __shared__ unsigned short lds[256 * 50];
    const int tid = threadIdx.x;
    const int vb = blockIdx.x % 125, b = blockIdx.x / 125;
    const int v0 = vb * 256;
    for (int tt = 0; tt < SEQ; ++tt)
        lds[tid * 50 + tt] = tmp[((size_t)tt * 16 + b) * NV + v0 + tid];
    __syncthreads();
    float* ob = out + ((size_t)b * NV + v0 + tid) * SEQ;
#pragma unroll
    for (int t4 = 0; t4 < 12; ++t4) {
        float4 v;
        v.x = b2f(lds[tid * 50 + t4 * 4 + 0]);
        v.y = b2f(lds[tid * 50 + t4 * 4 + 1]);
        v.z = b2f(lds[tid * 50 + t4 * 4 + 2]);
        v.w = b2f(lds[tid * 50 + t4 * 4 + 3]);
        *(float4*)(ob + t4 * 4) = v;
    }
}

extern "C" void kernel_launch(void* const* d_in, const int* in_sizes, int n_in,
                              void* d_out, int out_size, void* d_ws, size_t ws_size,
                              hipStream_t stream)
{
    const int*   x       = (const int*)d_in[0];
    const int*   y       = (const int*)d_in[1];
    const float* enc_emb = (const float*)d_in[2];
    const float* enc_Wih = (const float*)d_in[3];
    const float* enc_Whh = (const float*)d_in[4];
    const float* enc_bb  = (const float*)d_in[5];
    const float* dec_emb = (const float*)d_in[6];
    const float* dec_Wih = (const float*)d_in[7];
    const float* dec_Whh = (const float*)d_in[8];
    const float* dec_bb  = (const float*)d_in[9];
    const float* lin_W   = (const float*)d_in[10];
    const float* lin_b   = (const float*)d_in[11];
    float* out = (float*)d_out;

    char* ws = (char*)d_ws;
    int* flags            = (int*)ws;                                  // 64 KB total flag area
    unsigned short* demb  = (unsigned short*)(ws + 65536);             // 768 KB
    unsigned short* xsA   = (unsigned short*)(ws + 65536 + 786432);
    unsigned short* xsB   = (unsigned short*)(ws + 65536 + 2 * 786432);
    unsigned short* dech0 = (unsigned short*)(ws + 65536 + 3 * 786432);            // 256 KB
    float* decc0          = (float*)(ws + 65536 + 3 * 786432 + 262144);            // 512 KB
    unsigned short* ds    = (unsigned short*)(ws + 65536 + 3 * 786432 + 262144 + 524288);   // 12 MB
    unsigned short* ltmp  = (unsigned short*)(ws + 65536 + 3 * 786432 + 262144 + 524288 + (size_t)16 * 786432);

    // Gx (encoder input-GEMM staging, 2*2*48*16*1024*4 B = 12.58 MB) aliases ds:
    // used only during enc_v2; dec_pipe fully rewrites ds afterwards.
    float* Gx = (float*)ds;
    // flag layout (ints): recflag @0 (16*2*16=512), gxflag @512 (16*2*8*16=4096),
    // decoder flags @8192 as before.
    hipMemsetAsync(flags, 0, 65536, stream);
    embed_kernel<<<1536, 256, 0, stream>>>(x, y, enc_emb, dec_emb, xsA, demb);
    enc_v2<<<18, 512, 0, stream>>>(enc_Wih, enc_Whh, enc_bb, xsA, xsB, dech0, decc0,
                                   Gx, flags, flags + 512);
    dec_pipe<<<512, 256, 0, stream>>>(dec_Wih, dec_Whh, dec_bb, demb, dech0, decc0, ds, flags + 8192);
    final_gemm<<<500, 256, 0, stream>>>(ds + (size_t)15 * SEQ * 16 * 512, lin_W, lin_b, ltmp);
    transpose_out<<<2000, 256, 0, stream>>>(ltmp, out);
}

// Round 2
// 6234.127 us; speedup vs baseline: 1.0973x; 1.0973x over previous
//
#include <hip/hip_runtime.h>
#include <stdint.h>

#define SEQ 48
#define NL  16
#define NV  32000
#define POLLMAX 4000000

typedef short bf16x8 __attribute__((ext_vector_type(8)));
typedef float f32x4  __attribute__((ext_vector_type(4)));

__device__ __forceinline__ unsigned short f2b(float f) {
    union { float f; unsigned int u; } v; v.f = f;
    unsigned int r = (v.u + 0x7FFFu + ((v.u >> 16) & 1u)) >> 16;
    return (unsigned short)r;
}
__device__ __forceinline__ float b2f(unsigned short s) {
    union { float f; unsigned int u; } v; v.u = ((unsigned int)s) << 16;
    return v.f;
}
__device__ __forceinline__ bf16x8 load_w8(const float* p) {
    const float4* q = (const float4*)p;
    float4 a = q[0], b = q[1];
    bf16x8 r;
    r[0] = (short)f2b(a.x); r[1] = (short)f2b(a.y);
    r[2] = (short)f2b(a.z); r[3] = (short)f2b(a.w);
    r[4] = (short)f2b(b.x); r[5] = (short)f2b(b.y);
    r[6] = (short)f2b(b.z); r[7] = (short)f2b(b.w);
    return r;
}
__device__ __forceinline__ bf16x8 load_b8(const unsigned short* p) {
    return *(const bf16x8*)p;
}
__device__ __forceinline__ f32x4 mfma16(bf16x8 a, bf16x8 b, f32x4 c) {
    return __builtin_amdgcn_mfma_f32_16x16x32_bf16(a, b, c, 0, 0, 0);
}
__device__ __forceinline__ float sigm(float x) { return 1.0f / (1.0f + __expf(-x)); }
__device__ __forceinline__ float tanh_(float x) { return 1.0f - 2.0f / (__expf(2.0f * x) + 1.0f); }

// ---------------- embeddings: gather + bf16 ----------------
__global__ __launch_bounds__(256) void embed_kernel(
    const int* __restrict__ x, const int* __restrict__ y,
    const float* __restrict__ enc_emb, const float* __restrict__ dec_emb,
    unsigned short* __restrict__ xs, unsigned short* __restrict__ ds)
{
    int bid = blockIdx.x;             // 0..1535
    int which = bid >= 768;
    int r = which ? bid - 768 : bid;
    int t = r >> 4, b = r & 15;
    int tok = which ? y[b * SEQ + t] : x[b * SEQ + t];
    const float* src = (which ? dec_emb : enc_emb) + (size_t)tok * 512;
    unsigned short* dst = (which ? ds : xs) + ((size_t)t * 16 + b) * 512;
    for (int k = threadIdx.x; k < 512; k += 256) dst[k] = f2b(src[k]);
}

// ---------------- W_hh fp32 -> bf16 (once, grid-parallel) ----------------
__global__ __launch_bounds__(256) void wconv(
    const float* __restrict__ src, unsigned short* __restrict__ dst, int n4)
{
    int i = blockIdx.x * 256 + threadIdx.x;
    const int stride = gridDim.x * 256;
    for (; i < n4; i += stride) {
        float4 v = ((const float4*)src)[i];
        uint2 o;
        o.x = (unsigned)f2b(v.x) | ((unsigned)f2b(v.y) << 16);
        o.y = (unsigned)f2b(v.z) | ((unsigned)f2b(v.w) << 16);
        ((uint2*)dst)[i] = o;
    }
}

// ---------------- encoder v3 ----------------
// 18 WGs x 512 threads.
//  bid 0..15 : Stage A producers (Wih @ x + bias -> Gx), x-row staged in LDS,
//              value-cached polls on recurrence flags.
//  bid 16,17 : recurrence WG per direction. Whole Whh [1024x256] bf16 on ONE CU:
//              K-tiles 0..4 in NAMED registers (160 VGPR/lane), tiles 5,6 in LDS
//              (128 KB), tile 7 streamed from L2 each step (hidden under LDS).
//              h exchanged via LDS; c lane-local. 2 barriers/step, no global
//              round trip on the critical path.
// Register budget (rec wave): 160 wk + 32 gv + 32 acc + 8 cr + ~16 misc ~= 248.
// __launch_bounds__(512,1): VGPR cap 256 under either launch_bounds semantics
// (round-1's (512,2) capped at 128 -> mass spill -> 430 MB scratch writes).

#define FOR_RT(M) M(0) M(1) M(2) M(3) M(4) M(5) M(6) M(7)

#define DECLR(rt) bf16x8 wa##rt, wb##rt, wc##rt, wd##rt, we##rt, gv##rt; f32x4 ac##rt;

#define LOADW(rt) { const unsigned short* p_ = wL + ((rt) >> 1) * 65536 + ((rt) & 1) * 4096; \
    wa##rt = load_b8(p_);        wb##rt = load_b8(p_ + 32); \
    wc##rt = load_b8(p_ + 64);   wd##rt = load_b8(p_ + 96); \
    we##rt = load_b8(p_ + 128); \
    wlds[wv][rt][0][lane] = load_b8(p_ + 160); \
    wlds[wv][rt][1][lane] = load_b8(p_ + 192); }

#define LOADG(rt) gv##rt = load_b8(wL + ((rt) >> 1) * 65536 + ((rt) & 1) * 4096 + 224);

#define LOADACC(rt) { float4 t4_ = *(const float4*)(gxt + ((rt) >> 1) * 256 + ((rt) & 1) * 16); \
    ac##rt[0] = t4_.x; ac##rt[1] = t4_.y; ac##rt[2] = t4_.z; ac##rt[3] = t4_.w; }

#define MMAa(rt) ac##rt = mfma16(wa##rt, hf, ac##rt);
#define MMAb(rt) ac##rt = mfma16(wb##rt, hf, ac##rt);
#define MMAc(rt) ac##rt = mfma16(wc##rt, hf, ac##rt);
#define MMAd(rt) ac##rt = mfma16(wd##rt, hf, ac##rt);
#define MMAe(rt) ac##rt = mfma16(we##rt, hf, ac##rt);
#define MML0(rt) { bf16x8 wl_ = wlds[wv][rt][0][lane]; ac##rt = mfma16(wl_, hf, ac##rt); }
#define MML1(rt) { bf16x8 wl_ = wlds[wv][rt][1][lane]; ac##rt = mfma16(wl_, hf, ac##rt); }
#define MMG(rt)  ac##rt = mfma16(gv##rt, hf, ac##rt);

#define HF(kt) (*(const bf16x8*)&h_lds[ln][(kt) * 32 + q * 8])

#define ELEM(uh, Ai, Af, Ag, Ao, CR) { \
    unsigned short hb[4]; \
    _Pragma("unroll") \
    for (int r_ = 0; r_ < 4; ++r_) { \
        float c_ = (t == 0) ? 0.f : CR[r_]; \
        float cn_ = sigm(Af[r_]) * c_ + sigm(Ai[r_]) * tanh_(Ag[r_]); \
        CR[r_] = cn_; \
        hb[r_] = f2b(sigm(Ao[r_]) * tanh_(cn_)); \
    } \
    const int u_ = wv * 32 + (uh) * 16 + q * 4; \
    uint2 hv_; hv_.x = (unsigned)hb[0] | ((unsigned)hb[1] << 16); \
    hv_.y = (unsigned)hb[2] | ((unsigned)hb[3] << 16); \
    *(uint2*)&h_lds[ln][u_] = hv_; \
    unsigned long long hl_ = (unsigned long long)hv_.x | ((unsigned long long)hv_.y << 32); \
    __hip_atomic_store((unsigned long long*)(xout + ((size_t)t_src * 16 + ln) * 512 + dir * 256 + u_), \
                       hl_, __ATOMIC_RELAXED, __HIP_MEMORY_SCOPE_AGENT); \
    if (t == SEQ - 1) { \
        *(uint2*)(dec_h0 + ((size_t)l * 16 + ln) * 512 + dir * 256 + u_) = hv_; \
        float4 cv_; cv_.x = CR[0]; cv_.y = CR[1]; cv_.z = CR[2]; cv_.w = CR[3]; \
        *(float4*)(dec_c0 + ((size_t)l * 16 + ln) * 512 + dir * 256 + u_) = cv_; \
    } }

__global__ __launch_bounds__(512, 1) void enc_v3(
    const float* __restrict__ Wih,             // [NL][2][1024][512] fp32
    const unsigned short* __restrict__ whhb,   // [NL][2][1024][256] bf16 (pre-converted)
    const float* __restrict__ bias,            // [NL][2][1024]
    unsigned short* __restrict__ xsA, unsigned short* __restrict__ xsB, // [48][16][512] ping-pong
    unsigned short* __restrict__ dec_h0,       // [NL][16][512] bf16
    float* __restrict__ dec_c0,                // [NL][16][512] fp32
    float* __restrict__ Gx,                    // [2 par][2 dir][48][16][1024] fp32 (aliases ds)
    int* __restrict__ recflag,                 // [NL][2] stride 16 ints
    int* __restrict__ gxflag)                  // [NL][2][8] stride 16 ints
{
    const int tid = threadIdx.x, bid = blockIdx.x;
    const int wv = tid >> 6, lane = tid & 63, q = lane >> 4, ln = lane & 15;

    __shared__ bf16x8 wlds[8][8][2][64];        // 128 KB: Whh K-tiles 5,6 (lane-private)
    __shared__ unsigned short h_lds[16][264];   // 8.25 KB: h[b][unit]
    __shared__ unsigned short x_sh[16][528];    // 16.5 KB: Stage A x-row staging

    if (bid < 16) {
        // ================= Stage A: input-GEMM producers =================
        const int dir = bid >> 3, pblk = bid & 7;
        const int gate = wv >> 1, half = wv & 1;
        const int row0 = gate * 256 + pblk * 32 + half * 16;
        const int cb = tid >> 5, cc = tid & 31;
        for (int l = 0; l < NL; ++l) {
            bf16x8 aih[16];
            const float* wb = Wih + (((size_t)(l * 2 + dir) * 1024) + row0 + ln) * 512;
#pragma unroll
            for (int kt = 0; kt < 16; ++kt) aih[kt] = load_w8(wb + kt * 32 + q * 8);
            const float4 bias4 = *(const float4*)(bias + (size_t)(l * 2 + dir) * 1024 + row0 + q * 4);
            const unsigned short* xin = (l & 1) ? xsB : xsA;
            float* gxl = Gx + (size_t)((l & 1) * 2 + dir) * SEQ * 16 * 1024;
            int* myflag = gxflag + ((l * 2 + dir) * 8 + pblk) * 16;
            const int* rfprev = recflag + (l - 1) * 2 * 16;
            int seen = 0;
            for (int s = 0; s < SEQ; ++s) {
                const int t_src = dir ? (SEQ - 1 - s) : s;
                if (l > 0) {
                    // xs_l[t_src] full <=> own-dir rec(l-1) >= s+1 AND other-dir >= 48-s
                    if (tid < 64) {
                        if (tid < 2) {
                            const int need = (tid == dir) ? (s + 1) : (SEQ - s);
                            if (seen < need) {
                                const int* f = rfprev + tid * 16;
                                int v = __hip_atomic_load(f, __ATOMIC_RELAXED, __HIP_MEMORY_SCOPE_AGENT);
                                int it = 0;
                                while (v < need && ++it <= POLLMAX)
                                    v = __hip_atomic_load(f, __ATOMIC_RELAXED, __HIP_MEMORY_SCOPE_AGENT);
                                seen = v;
                            }
                        }
                        __builtin_amdgcn_fence(__ATOMIC_ACQUIRE, "agent");
                    }
                    __syncthreads();
                }
                // stage x row into LDS (one global read instead of 8 per-wave reads)
                {
                    const unsigned short* sr = xin + ((size_t)t_src * 16 + cb) * 512 + cc * 8;
                    *(bf16x8*)&x_sh[cb][cc * 8] = load_b8(sr);
                    *(bf16x8*)&x_sh[cb][cc * 8 + 256] = load_b8(sr + 256);
                }
                __syncthreads();
                f32x4 acc0 = {0.f,0.f,0.f,0.f}, acc1 = {0.f,0.f,0.f,0.f};
#pragma unroll
                for (int kt = 0; kt < 16; kt += 2) {
                    acc0 = mfma16(aih[kt],     load_b8(&x_sh[ln][kt * 32 + q * 8]),       acc0);
                    acc1 = mfma16(aih[kt + 1], load_b8(&x_sh[ln][(kt + 1) * 32 + q * 8]), acc1);
                }
                {
                    float g0 = acc0[0] + acc1[0] + bias4.x;
                    float g1 = acc0[1] + acc1[1] + bias4.y;
                    float g2 = acc0[2] + acc1[2] + bias4.z;
                    float g3 = acc0[3] + acc1[3] + bias4.w;
                    unsigned long long u0 = (unsigned long long)__float_as_uint(g0) |
                                            ((unsigned long long)__float_as_uint(g1) << 32);
                    unsigned long long u1 = (unsigned long long)__float_as_uint(g2) |
                                            ((unsigned long long)__float_as_uint(g3) << 32);
                    unsigned long long* gd =
                        (unsigned long long*)(gxl + ((size_t)t_src * 16 + ln) * 1024 + row0 + q * 4);
                    __hip_atomic_store(gd,     u0, __ATOMIC_RELAXED, __HIP_MEMORY_SCOPE_AGENT);
                    __hip_atomic_store(gd + 1, u1, __ATOMIC_RELAXED, __HIP_MEMORY_SCOPE_AGENT);
                }
                __syncthreads();
                if (tid == 0)
                    __hip_atomic_store(myflag, s + 1, __ATOMIC_RELEASE, __HIP_MEMORY_SCOPE_AGENT);
            }
        }
        return;
    }

    // ================= recurrence: one WG per direction =================
    const int dir = bid - 16;
    FOR_RT(DECLR)
    f32x4 cr0 = {0.f,0.f,0.f,0.f}, cr1 = {0.f,0.f,0.f,0.f};

    for (int l = 0; l < NL; ++l) {
        const unsigned short* wL = whhb + (size_t)(l * 2 + dir) * 262144
                                 + (size_t)(wv * 32 + ln) * 256 + q * 8;
        FOR_RT(LOADW)
        const int* gxf = gxflag + (l * 2 + dir) * 8 * 16;
        int* rf = recflag + (l * 2 + dir) * 16;
        const float* gxl = Gx + (size_t)((l & 1) * 2 + dir) * SEQ * 16 * 1024;
        unsigned short* xout = (l & 1) ? xsA : xsB;
        int seen = 0;
        __syncthreads();

        for (int t = 0; t < SEQ; ++t) {
            const int t_src = dir ? (SEQ - 1 - t) : t;
            // wait for Gx chunk t from this direction's 8 producers (value-cached)
            if (tid < 64) {
                if (tid < 8 && seen < t + 1) {
                    const int* f = gxf + tid * 16;
                    int v = __hip_atomic_load(f, __ATOMIC_RELAXED, __HIP_MEMORY_SCOPE_AGENT);
                    int it = 0;
                    while (v < t + 1 && ++it <= POLLMAX)
                        v = __hip_atomic_load(f, __ATOMIC_RELAXED, __HIP_MEMORY_SCOPE_AGENT);
                    seen = v;
                }
                __builtin_amdgcn_fence(__ATOMIC_ACQUIRE, "agent");
            }
            __syncthreads();
            // lagged release: step t-1's xout stores are drained by the barrier above
            if (tid == 0 && t > 0)
                __hip_atomic_store(rf, t, __ATOMIC_RELEASE, __HIP_MEMORY_SCOPE_AGENT);

            // acc init from Gx (bias already folded in)
            const float* gxt = gxl + ((size_t)t_src * 16 + ln) * 1024 + wv * 32 + q * 4;
            FOR_RT(LOADACC)
            if (t > 0) {
                FOR_RT(LOADG)               // K-tile 7 from L2 (lands under kt0..6)
                bf16x8 hf;
                hf = HF(0); FOR_RT(MMAa)
                hf = HF(1); FOR_RT(MMAb)
                hf = HF(2); FOR_RT(MMAc)
                hf = HF(3); FOR_RT(MMAd)
                hf = HF(4); FOR_RT(MMAe)
                hf = HF(5); FOR_RT(MML0)
                hf = HF(6); FOR_RT(MML1)
                hf = HF(7); FOR_RT(MMG)
            }
            __syncthreads();                // all h_lds reads done before overwrite

            // lane-local LSTM update (gates i,f,g,o live in ac0..7 of this lane)
            ELEM(0, ac0, ac2, ac4, ac6, cr0)
            ELEM(1, ac1, ac3, ac5, ac7, cr1)
            // next iteration's poll-barrier separates h_lds writes from reads
        }
        __syncthreads();
        if (tid == 0)
            __hip_atomic_store(rf, SEQ, __ATOMIC_RELEASE, __HIP_MEMORY_SCOPE_AGENT);
    }
}

// ---------------- pipelined decoder: ALL 16 layers concurrent, 512 WGs ----------------
__global__ __launch_bounds__(256, 2) void dec_pipe(
    const float* __restrict__ Wih,   // [NL][2048][512]
    const float* __restrict__ Whh,   // [NL][2048][512]
    const float* __restrict__ bias,  // [NL][2048]
    const unsigned short* __restrict__ demb, // [48][16][512]
    const unsigned short* __restrict__ h0,   // [NL][16][512]
    const float* __restrict__ c0,            // [NL][16][512]
    unsigned short* __restrict__ ds,         // [NL][48][16][512]
    int* __restrict__ flags)                 // [NL][32] stride 16 ints
{
    const int tid = threadIdx.x;
    const int l = blockIdx.x >> 5, p = blockIdx.x & 31;
    const int gate = tid >> 6, lane = tid & 63, q = lane >> 4, ln = lane & 15;
    __shared__ float gsm[4][16][17];
    __shared__ float cbuf[16][17];

    bf16x8 aih[16], ahh[16];
    const size_t row = (size_t)l * 2048 + gate * 512 + p * 16 + ln;
#pragma unroll
    for (int kt = 0; kt < 16; ++kt) aih[kt] = load_w8(Wih + row * 512 + kt * 32 + q * 8);
#pragma unroll
    for (int kt = 0; kt < 16; ++kt) ahh[kt] = load_w8(Whh + row * 512 + kt * 32 + q * 8);
    const float4 bias4 = *(const float4*)(bias + (size_t)l * 2048 + gate * 512 + p * 16 + q * 4);

    const unsigned short* xlayer = (l == 0) ? demb : (ds + (size_t)(l - 1) * SEQ * 16 * 512);
    const int* fin  = flags + (l - 1) * 32 * 16;
    const int* fown = flags + l * 32 * 16;
    int* myflag = flags + (l * 32 + p) * 16;

    for (int t = 0; t < SEQ; ++t) {
        if (tid < 64) {
            if (tid < 32) {
                if (l > 0) {
                    const int* f = fin + tid * 16;
                    int it = 0;
                    while (__hip_atomic_load(f, __ATOMIC_RELAXED, __HIP_MEMORY_SCOPE_AGENT) < t + 1)
                        if (++it > POLLMAX) break;
                }
            } else if (t > 0) {
                const int* f = fown + (tid - 32) * 16;
                int it = 0;
                while (__hip_atomic_load(f, __ATOMIC_RELAXED, __HIP_MEMORY_SCOPE_AGENT) < t)
                    if (++it > POLLMAX) break;
            }
            __builtin_amdgcn_fence(__ATOMIC_ACQUIRE, "agent");
        }
        __syncthreads();

        const unsigned short* xrow = xlayer + ((size_t)t * 16 + ln) * 512;
        const unsigned short* hrow = (t == 0) ? (h0 + ((size_t)l * 16 + ln) * 512)
                                              : (ds + (((size_t)l * SEQ + (t - 1)) * 16 + ln) * 512);
        f32x4 acc0 = {0.f,0.f,0.f,0.f}, acc1 = {0.f,0.f,0.f,0.f};
#pragma unroll
        for (int kt = 0; kt < 16; kt += 2) {
            acc0 = mfma16(aih[kt],     load_b8(xrow + kt * 32 + q * 8),       acc0);
            acc1 = mfma16(aih[kt + 1], load_b8(xrow + (kt + 1) * 32 + q * 8), acc1);
        }
#pragma unroll
        for (int kt = 0; kt < 16; kt += 2) {
            acc0 = mfma16(ahh[kt],     load_b8(hrow + kt * 32 + q * 8),       acc0);
            acc1 = mfma16(ahh[kt + 1], load_b8(hrow + (kt + 1) * 32 + q * 8), acc1);
        }
        gsm[gate][q * 4 + 0][ln] = acc0[0] + acc1[0] + bias4.x;
        gsm[gate][q * 4 + 1][ln] = acc0[1] + acc1[1] + bias4.y;
        gsm[gate][q * 4 + 2][ln] = acc0[2] + acc1[2] + bias4.z;
        gsm[gate][q * 4 + 3][ln] = acc0[3] + acc1[3] + bias4.w;
        __syncthreads();
        if (tid < 128) {
            const int b = tid >> 3, u2 = (tid & 7) * 2;
            unsigned int hv = 0;
#pragma unroll
            for (int s = 0; s < 2; ++s) {
                int u = u2 + s;
                float gi = gsm[0][u][b], gf = gsm[1][u][b], gg = gsm[2][u][b], go = gsm[3][u][b];
                float c = (t == 0) ? c0[((size_t)l * 16 + b) * 512 + p * 16 + u] : cbuf[u][b];
                float cn = sigm(gf) * c + sigm(gi) * tanh_(gg);
                float h = sigm(go) * tanh_(cn);
                cbuf[u][b] = cn;
                hv |= ((unsigned int)f2b(h)) << (16 * s);
            }
            __hip_atomic_store((unsigned int*)(ds + (((size_t)l * SEQ + t) * 16 + b) * 512 + p * 16 + u2),
                               hv, __ATOMIC_RELAXED, __HIP_MEMORY_SCOPE_AGENT);
        }
        __syncthreads();
        if (tid == 0)
            __hip_atomic_store(myflag, t + 1, __ATOMIC_RELEASE, __HIP_MEMORY_SCOPE_AGENT);
    }
}

// ---------------- final projection ----------------
__global__ __launch_bounds__(256) void final_gemm(
    const unsigned short* __restrict__ ds,
    const float* __restrict__ W,
    const float* __restrict__ bias,
    unsigned short* __restrict__ out)
{
    const int tid = threadIdx.x;
    const int w = tid >> 6, lane = tid & 63, q = lane >> 4, ln = lane & 15;
    const int n0 = blockIdx.x * 64;     // 500 blocks
    for (int mb = 0; mb < 12; ++mb) {
        const int m0 = mb * 64 + w * 16;
        bf16x8 afr[16];
#pragma unroll
        for (int kt = 0; kt < 16; ++kt)
            afr[kt] = load_b8(ds + ((size_t)m0 + ln) * 512 + kt * 32 + q * 8);
#pragma unroll
        for (int j = 0; j < 4; ++j) {
            f32x4 acc0 = {0.f,0.f,0.f,0.f}, acc1 = {0.f,0.f,0.f,0.f};
            const float* wb = W + ((size_t)(n0 + j * 16 + ln)) * 512;
#pragma unroll
            for (int kt = 0; kt < 16; kt += 2) {
                bf16x8 b0 = load_w8(wb + kt * 32 + q * 8);
                bf16x8 b1 = load_w8(wb + (kt + 1) * 32 + q * 8);
                acc0 = mfma16(afr[kt], b0, acc0);
                acc1 = mfma16(afr[kt + 1], b1, acc1);
            }
            int n = n0 + j * 16 + ln;
            float bv = bias[n];
#pragma unroll
            for (int r = 0; r < 4; ++r)
                out[((size_t)m0 + q * 4 + r) * NV + n] = f2b(acc0[r] + acc1[r] + bv);
        }
    }
}

// ---------------- transpose: out[b][v][t] (fp32) from ltmp[t*16+b][v] (bf16) ----------------
__global__ __launch_bounds__(256) void transpose_out(
    const unsigned short* __restrict__ tmp, float* __restrict__ out)
{
    __shared__ unsigned short lds[256 * 50];
    const int tid = threadIdx.x;
    const int vb = blockIdx.x % 125, b = blockIdx.x / 125;
    const int v0 = vb * 256;
    for (int tt = 0; tt < SEQ; ++tt)
        lds[tid * 50 + tt] = tmp[((size_t)tt * 16 + b) * NV + v0 + tid];
    __syncthreads();
    float* ob = out + ((size_t)b * NV + v0 + tid) * SEQ;
#pragma unroll
    for (int t4 = 0; t4 < 12; ++t4) {
        float4 v;
        v.x = b2f(lds[tid * 50 + t4 * 4 + 0]);
        v.y = b2f(lds[tid * 50 + t4 * 4 + 1]);
        v.z = b2f(lds[tid * 50 + t4 * 4 + 2]);
        v.w = b2f(lds[tid * 50 + t4 * 4 + 3]);
        *(float4*)(ob + t4 * 4) = v;
    }
}

extern "C" void kernel_launch(void* const* d_in, const int* in_sizes, int n_in,
                              void* d_out, int out_size, void* d_ws, size_t ws_size,
                              hipStream_t stream)
{
    const int*   x       = (const int*)d_in[0];
    const int*   y       = (const int*)d_in[1];
    const float* enc_emb = (const float*)d_in[2];
    const float* enc_Wih = (const float*)d_in[3];
    const float* enc_Whh = (const float*)d_in[4];
    const float* enc_bb  = (const float*)d_in[5];
    const float* dec_emb = (const float*)d_in[6];
    const float* dec_Wih = (const float*)d_in[7];
    const float* dec_Whh = (const float*)d_in[8];
    const float* dec_bb  = (const float*)d_in[9];
    const float* lin_W   = (const float*)d_in[10];
    const float* lin_b   = (const float*)d_in[11];
    float* out = (float*)d_out;

    char* ws = (char*)d_ws;
    int* flags            = (int*)ws;                                  // 64 KB flag area
    unsigned short* demb  = (unsigned short*)(ws + 65536);             // 768 KB
    unsigned short* xsA   = (unsigned short*)(ws + 65536 + 786432);
    unsigned short* xsB   = (unsigned short*)(ws + 65536 + 2 * 786432);
    unsigned short* dech0 = (unsigned short*)(ws + 65536 + 3 * 786432);            // 256 KB
    float* decc0          = (float*)(ws + 65536 + 3 * 786432 + 262144);            // 512 KB
    unsigned short* ds    = (unsigned short*)(ws + 65536 + 3 * 786432 + 262144 + 524288);   // 12 MB
    unsigned short* ltmp  = (unsigned short*)(ws + 65536 + 3 * 786432 + 262144 + 524288 + (size_t)16 * 786432);

    // Gx (encoder input-GEMM staging, 12.58 MB) aliases ds (dec_pipe rewrites it later).
    float* Gx = (float*)ds;
    // whhb (pre-converted enc W_hh bf16, 16.78 MB) aliases ltmp (final_gemm writes it later).
    unsigned short* whhb = ltmp;
    // flag layout (ints): recflag @0 (512), gxflag @512 (4096), decoder flags @8192.
    hipMemsetAsync(flags, 0, 65536, stream);
    embed_kernel<<<1536, 256, 0, stream>>>(x, y, enc_emb, dec_emb, xsA, demb);
    wconv<<<2048, 256, 0, stream>>>(enc_Whh, whhb, NL * 2 * 1024 * 256 / 4);
    enc_v3<<<18, 512, 0, stream>>>(enc_Wih, whhb, enc_bb, xsA, xsB, dech0, decc0,
                                   Gx, flags, flags + 512);
    dec_pipe<<<512, 256, 0, stream>>>(dec_Wih, dec_Whh, dec_bb, demb, dech0, decc0, ds, flags + 8192);
    final_gemm<<<500, 256, 0, stream>>>(ds + (size_t)15 * SEQ * 16 * 512, lin_W, lin_b, ltmp);
    transpose_out<<<2000, 256, 0, stream>>>(ltmp, out);
}